// Round 10
// baseline (387.207 us; speedup 1.0000x reference)
//
#include <hip/hip_runtime.h>
#include <hip/hip_bf16.h>
#include <stdint.h>

typedef unsigned short ushort_t;
using short8   = __attribute__((ext_vector_type(8))) short;
using float4v  = __attribute__((ext_vector_type(4))) float;
using uint4v   = __attribute__((ext_vector_type(4))) unsigned;
using uint2v   = __attribute__((ext_vector_type(2))) unsigned;

#define BSH    6          // bucket = 64 consecutive dst nodes
#define BUCKW  64
#define CAP    1536       // per-bucket capacity (avg 1024, +16 sigma)
#define NBMAX  2048
#define BINB   384        // binning blocks (512 thr each)
#define HPITCH 136
#define APITCH 36         // agg_s pitch in dwords

__device__ __forceinline__ ushort_t f2b(float f) {
    union { float f; unsigned int i; } v;
    v.f = f;
    unsigned int u = v.i;
    unsigned int r = (u + 0x7fffu + ((u >> 16) & 1u)) >> 16;   // RNE
    return (ushort_t)r;
}
__device__ __forceinline__ float blo2f(unsigned v) {
    union { unsigned i; float f; } u; u.i = v << 16; return u.f;
}
__device__ __forceinline__ float bhi2f(unsigned v) {
    union { unsigned i; float f; } u; u.i = v & 0xFFFF0000u; return u.f;
}

// ---------------------------------------------------------------------------
// prep_k: heterogeneous roles, 512 threads.
//  binning (blocks [0,BINB)): SINGLE-SWEEP via global atomics — per edge:
//    pos = atomicAdd(&gcur[bucket],1); bin write. Replaces the two-sweep
//    LDS counting apparatus (6.4MB dst re-read + LDS hist/scan + 24KB LDS).
//    Order within a bucket is arbitrary -> fine, bam_k re-sorts per bucket.
//  transpose (blocks [BINB,..)): register-direct, R5-verified body unchanged.
//  prep now uses NO LDS -> no LDS occupancy cap for either role.
// ---------------------------------------------------------------------------
__global__ __launch_bounds__(512) void prep_k(
        const float* __restrict__ inp, ushort_t* __restrict__ X, int N,
        const float* __restrict__ W1, const float* __restrict__ W2,
        ushort_t* __restrict__ w1b, ushort_t* __restrict__ w2b,
        const int* __restrict__ src, const int* __restrict__ dst,
        int* __restrict__ gcur, unsigned* __restrict__ bin, int E,
        int NB) {
    int tid = threadIdx.x;

    if ((int)blockIdx.x >= BINB) {
        // ---------------- transpose role (register-direct) ----------------
        int tb = blockIdx.x - BINB;
        if (tb == 0) {
            for (int i = tid; i < 8192; i += 512) {
                w1b[i] = f2b(W1[i]);
                w2b[i] = f2b(W2[i]);
            }
        }
        int db = tid >> 7;                  // 0..3: 16-dim block
        int nl = tid & 127;                 // node within block tile
        int nc = tb * 128 + nl;
        if (nc < N) {
            const float* ip = inp + (size_t)(db * 16) * N + nc;
            float v[16];
#pragma unroll
            for (int r = 0; r < 16; ++r)    // 16 independent loads -> in flight
                v[r] = ip[(size_t)r * N];
            unsigned dw[8];
#pragma unroll
            for (int j = 0; j < 8; ++j)
                dw[j] = (unsigned)f2b(v[2 * j]) | ((unsigned)f2b(v[2 * j + 1]) << 16);
            unsigned* xp = (unsigned*)X + (size_t)nc * 32 + db * 8;
            uint4v a = {dw[0], dw[1], dw[2], dw[3]};
            uint4v b = {dw[4], dw[5], dw[6], dw[7]};
            *(uint4v*)(xp)     = a;
            *(uint4v*)(xp + 4) = b;
        }
    } else {
        // ---------------- binning role: single sweep, global atomics ------
        int bid   = blockIdx.x;
        int chunk = (E + BINB - 1) / BINB;
        int s0 = bid * chunk;
        int s1 = s0 + chunk;
        if (s1 > E) s1 = E;

        int e = s0 + tid;
        for (; e + 512 * 7 < s1; e += 512 * 8) {
            int d[8], s[8];
#pragma unroll
            for (int k = 0; k < 8; ++k) {
                d[k] = dst[e + 512 * k];
                s[k] = src[e + 512 * k];
            }
#pragma unroll
            for (int k = 0; k < 8; ++k) {
                int b   = d[k] >> BSH;
                int pos = atomicAdd(&gcur[b], 1);
                if (pos < CAP)   // overflow guard (statistically unreachable)
                    bin[(size_t)b * CAP + pos] =
                        ((unsigned)(d[k] & (BUCKW - 1)) << 24) | (unsigned)s[k];
            }
        }
        for (; e < s1; e += 512) {
            int dv = dst[e];
            int b  = dv >> BSH;
            int pos = atomicAdd(&gcur[b], 1);
            if (pos < CAP)
                bin[(size_t)b * CAP + pos] =
                    ((unsigned)(dv & (BUCKW - 1)) << 24) | (unsigned)src[e];
        }
    }
}

// ---------------------------------------------------------------------------
// bam_k: fused sort + gather + MLP, 512 threads — EXACT R8 body (verified
// 64 us; dwordx2 gather is the measured sweet spot, R9's dwordx4 was -3us).
// Each lane loads 8B (2 dims); one wave instruction covers FOUR edge rows:
// qtr=lane>>4 picks edge e+qtr, du=lane&15 picks the uint2 within the row.
// Cross-lane combine: shfl_xor(16)+shfl_xor(32); lanes 0-15 write 2 dwords.
// LDS union (17408 B): sl@0 | ecnt/sc/ecur@6144 | agg_s@6912; h_s overlays
// after the post-gather barrier. MLP: R6 wave-pair split (verified).
// ---------------------------------------------------------------------------
__global__ __launch_bounds__(512, 3) void bam_k(
        const unsigned* __restrict__ Xu, const unsigned* __restrict__ bin,
        const int* __restrict__ gcur,
        const ushort_t* __restrict__ W1, const float* __restrict__ b1,
        const ushort_t* __restrict__ W2, const float* __restrict__ b2,
        float* __restrict__ out, int N) {
    __shared__ __align__(16) char P[17408];
    unsigned* sl    = (unsigned*)P;                 // [0, 6144)
    int*      ecnt  = (int*)(P + 6144);             // [6144, 6400)
    int*      sc    = (int*)(P + 6400);             // [6400, 6656)
    int*      ecur  = (int*)(P + 6656);             // [6656, 6912)
    unsigned* agg_s = (unsigned*)(P + 6912);        // [6912, 16128)

    int tid = threadIdx.x;
    int b   = blockIdx.x;

    int cnt = gcur[b];
    if (cnt > CAP) cnt = CAP;
    const unsigned* bb = bin + (size_t)b * CAP;

    if (tid < BUCKW) ecnt[tid] = 0;
    __syncthreads();

    for (int i = tid; i < cnt; i += 512)
        atomicAdd(&ecnt[bb[i] >> 24], 1);
    __syncthreads();

    if (tid < BUCKW) {                      // single-wave inclusive scan
        int v = ecnt[tid];
#pragma unroll
        for (int off = 1; off < BUCKW; off <<= 1) {
            int t = __shfl_up(v, off, 64);
            if (tid >= off) v += t;
        }
        sc[tid]   = v - ecnt[tid];          // exclusive
        ecur[tid] = 0;
    }
    __syncthreads();

    for (int i = tid; i < cnt; i += 512) {
        unsigned p = bb[i];
        int nl  = (int)(p >> 24);
        int pos = sc[nl] + atomicAdd(&ecur[nl], 1);
        sl[pos] = p;
    }
    __syncthreads();

    const uint2v* Xu2 = (const uint2v*)Xu;   // row = 16 uint2 (128 B)

    int wave = tid >> 6;               // 0..7
    int lane = tid & 63;
    int qtr  = lane >> 4;              // 0..3: which of 4 edges per instr
    unsigned du = (unsigned)(lane & 15);   // uint2 index within row (dims 4du..4du+3)
    int row  = lane & 15;
    int quad = lane >> 4;

    for (int n = wave; n < BUCKW; n += 8) {
        int s0 = sc[n];
        int c  = ecnt[n];              // 0 for out-of-range nodes -> zeros
        float a0f = 0.f, a1f = 0.f, a2f = 0.f, a3f = 0.f;
        int i = 0;
        for (; i + 16 <= c; i += 16) {     // 16 edges = 4 load instrs
            unsigned p0 = sl[s0 + i +  0 + qtr];
            unsigned p1 = sl[s0 + i +  4 + qtr];
            unsigned p2 = sl[s0 + i +  8 + qtr];
            unsigned p3 = sl[s0 + i + 12 + qtr];
            uint2v v0 = Xu2[((p0 & 0xFFFFFFu) << 4) | du];
            uint2v v1 = Xu2[((p1 & 0xFFFFFFu) << 4) | du];
            uint2v v2 = Xu2[((p2 & 0xFFFFFFu) << 4) | du];
            uint2v v3 = Xu2[((p3 & 0xFFFFFFu) << 4) | du];
            a0f += blo2f(v0[0]); a1f += bhi2f(v0[0]);
            a2f += blo2f(v0[1]); a3f += bhi2f(v0[1]);
            a0f += blo2f(v1[0]); a1f += bhi2f(v1[0]);
            a2f += blo2f(v1[1]); a3f += bhi2f(v1[1]);
            a0f += blo2f(v2[0]); a1f += bhi2f(v2[0]);
            a2f += blo2f(v2[1]); a3f += bhi2f(v2[1]);
            a0f += blo2f(v3[0]); a1f += bhi2f(v3[0]);
            a2f += blo2f(v3[1]); a3f += bhi2f(v3[1]);
        }
        for (; i + 4 <= c; i += 4) {
            unsigned p = sl[s0 + i + qtr];
            uint2v v = Xu2[((p & 0xFFFFFFu) << 4) | du];
            a0f += blo2f(v[0]); a1f += bhi2f(v[0]);
            a2f += blo2f(v[1]); a3f += bhi2f(v[1]);
        }
        if (i < c && qtr < c - i) {        // tail 1..3 edges
            unsigned p = sl[s0 + i + qtr];
            uint2v v = Xu2[((p & 0xFFFFFFu) << 4) | du];
            a0f += blo2f(v[0]); a1f += bhi2f(v[0]);
            a2f += blo2f(v[1]); a3f += bhi2f(v[1]);
        }
        // butterfly across the 4 qtr-groups (lanes du, du+16, du+32, du+48)
        a0f += __shfl_xor(a0f, 16); a1f += __shfl_xor(a1f, 16);
        a2f += __shfl_xor(a2f, 16); a3f += __shfl_xor(a3f, 16);
        a0f += __shfl_xor(a0f, 32); a1f += __shfl_xor(a1f, 32);
        a2f += __shfl_xor(a2f, 32); a3f += __shfl_xor(a3f, 32);
        if (qtr == 0) {
            agg_s[n * APITCH + 2 * (int)du]     =
                (unsigned)f2b(a0f) | ((unsigned)f2b(a1f) << 16);
            agg_s[n * APITCH + 2 * (int)du + 1] =
                (unsigned)f2b(a2f) | ((unsigned)f2b(a3f) << 16);
        }
    }
    __syncthreads();    // gather complete (sl dead; agg_s valid)

    // ---------------- fused MLP, wave-pair split (R6/R8 verified) ----------------
    int grp    = wave & 3;             // node group: rows grp*16 .. +15
    int g_half = wave >> 2;            // 0: dims/cols 0-63|0-31, 1: the rest

    const unsigned* arow = agg_s + (grp * 16 + row) * APITCH;
    short8 a0 = *(const short8*)(arow + quad * 4);
    short8 a1 = *(const short8*)(arow + 16 + quad * 4);

    __syncthreads();    // all A-fragments in registers; agg_s region now free

    ushort_t* hw = (ushort_t*)P + (size_t)grp * (16 * HPITCH);
    float4v zero = {0.f, 0.f, 0.f, 0.f};

    // layer 1: this wave computes dim-half g_half (64 of 128 hidden dims)
    {
        float4v acc[4];
#pragma unroll
        for (int nt = 0; nt < 4; ++nt) acc[nt] = zero;
#pragma unroll
        for (int nt = 0; nt < 4; ++nt) {
            const ushort_t* wp = W1 + (size_t)(g_half * 64 + nt * 16 + row) * 64 + quad * 8;
            short8 bf0 = *(const short8*)(wp);
            short8 bf1 = *(const short8*)(wp + 32);
            acc[nt] = __builtin_amdgcn_mfma_f32_16x16x32_bf16(a0, bf0, acc[nt], 0, 0, 0);
            acc[nt] = __builtin_amdgcn_mfma_f32_16x16x32_bf16(a1, bf1, acc[nt], 0, 0, 0);
        }
#pragma unroll
        for (int nt = 0; nt < 4; ++nt) {
            float bias = b1[g_half * 64 + nt * 16 + row];
#pragma unroll
            for (int r = 0; r < 4; ++r) {
                float v = acc[nt][r] + bias;
                v = v > 0.f ? v : 0.f;
                hw[(quad * 4 + r) * HPITCH + g_half * 64 + nt * 16 + row] = f2b(v);
            }
        }
    }
    __syncthreads();

    short8 a2[4];
#pragma unroll
    for (int kt = 0; kt < 4; ++kt)
        a2[kt] = *(const short8*)(hw + row * HPITCH + kt * 32 + quad * 8);

    // layer 2: this wave computes out-col tiles {g_half*2, g_half*2+1}
    float4v acc2[2];
#pragma unroll
    for (int nt = 0; nt < 2; ++nt) acc2[nt] = zero;

#pragma unroll
    for (int nt = 0; nt < 2; ++nt) {
        int ntg = g_half * 2 + nt;
#pragma unroll
        for (int kt = 0; kt < 4; ++kt) {
            short8 bfr = *(const short8*)(W2 + (size_t)(ntg * 16 + row) * 128 +
                                          kt * 32 + quad * 8);
            acc2[nt] = __builtin_amdgcn_mfma_f32_16x16x32_bf16(a2[kt], bfr, acc2[nt], 0, 0, 0);
        }
    }

    int n0   = (b << BSH) + grp * 16;
    int node = n0 + quad * 4;
#pragma unroll
    for (int nt = 0; nt < 2; ++nt) {
        int ko = (g_half * 2 + nt) * 16 + row;
        float bias = b2[ko];
        float4v pk;
#pragma unroll
        for (int r = 0; r < 4; ++r) pk[r] = acc2[nt][r] + bias;
        if (node + 3 < N) {
            *(float4v*)(out + (size_t)ko * N + node) = pk;
        } else {
#pragma unroll
            for (int r = 0; r < 4; ++r)
                if (node + r < N) out[(size_t)ko * N + node + r] = pk[r];
        }
    }
}

// ---------------------------------------------------------------------------
// Fallback pair (small-ws path): R1/R2 verified bagg_k + mlp_k.
// ---------------------------------------------------------------------------
__global__ __launch_bounds__(256) void bagg_k(
        const unsigned* __restrict__ Xu, const unsigned* __restrict__ bin,
        const int* __restrict__ gcur, unsigned* __restrict__ aggu, int N) {
    __shared__ unsigned sl[CAP];
    __shared__ int ecnt[BUCKW];
    __shared__ int sc[BUCKW];
    __shared__ int ecur[BUCKW];
    int tid = threadIdx.x;
    int b   = blockIdx.x;
    int lo  = b << BSH;

    int cnt = gcur[b];
    if (cnt > CAP) cnt = CAP;
    const unsigned* bb = bin + (size_t)b * CAP;

    if (tid < BUCKW) ecnt[tid] = 0;
    __syncthreads();
    for (int i = tid; i < cnt; i += 256)
        atomicAdd(&ecnt[bb[i] >> 24], 1);
    __syncthreads();
    if (tid < BUCKW) sc[tid] = ecnt[tid];
    __syncthreads();
#pragma unroll
    for (int off = 1; off < BUCKW; off <<= 1) {
        int v = 0;
        if (tid < BUCKW && tid >= off) v = sc[tid - off];
        __syncthreads();
        if (tid < BUCKW) sc[tid] += v;
        __syncthreads();
    }
    if (tid < BUCKW) { sc[tid] -= ecnt[tid]; ecur[tid] = 0; }
    __syncthreads();
    for (int i = tid; i < cnt; i += 256) {
        unsigned p = bb[i];
        int nl  = (int)(p >> 24);
        int pos = sc[nl] + atomicAdd(&ecur[nl], 1);
        sl[pos] = p;
    }
    __syncthreads();

    int wave = tid >> 6;
    int lane = tid & 63;
    int half = lane >> 5;
    unsigned cu = (unsigned)(lane & 31);

    for (int n = wave; n < BUCKW; n += 4) {
        int node = lo + n;
        if (node >= N) break;
        int s0 = sc[n];
        int c  = ecnt[n];
        float alo0 = 0.f, ahi0 = 0.f, alo1 = 0.f, ahi1 = 0.f;
        int i = 0;
        for (; i + 16 <= c; i += 16) {
            unsigned p0 = sl[s0 + i +  0 + half], p1 = sl[s0 + i +  2 + half];
            unsigned p2 = sl[s0 + i +  4 + half], p3 = sl[s0 + i +  6 + half];
            unsigned p4 = sl[s0 + i +  8 + half], p5 = sl[s0 + i + 10 + half];
            unsigned p6 = sl[s0 + i + 12 + half], p7 = sl[s0 + i + 14 + half];
            unsigned v0 = Xu[((p0 & 0xFFFFFFu) << 5) | cu];
            unsigned v1 = Xu[((p1 & 0xFFFFFFu) << 5) | cu];
            unsigned v2 = Xu[((p2 & 0xFFFFFFu) << 5) | cu];
            unsigned v3 = Xu[((p3 & 0xFFFFFFu) << 5) | cu];
            unsigned v4 = Xu[((p4 & 0xFFFFFFu) << 5) | cu];
            unsigned v5 = Xu[((p5 & 0xFFFFFFu) << 5) | cu];
            unsigned v6 = Xu[((p6 & 0xFFFFFFu) << 5) | cu];
            unsigned v7 = Xu[((p7 & 0xFFFFFFu) << 5) | cu];
            alo0 += blo2f(v0); ahi0 += bhi2f(v0);
            alo1 += blo2f(v1); ahi1 += bhi2f(v1);
            alo0 += blo2f(v2); ahi0 += bhi2f(v2);
            alo1 += blo2f(v3); ahi1 += bhi2f(v3);
            alo0 += blo2f(v4); ahi0 += bhi2f(v4);
            alo1 += blo2f(v5); ahi1 += bhi2f(v5);
            alo0 += blo2f(v6); ahi0 += bhi2f(v6);
            alo1 += blo2f(v7); ahi1 += bhi2f(v7);
        }
        for (; i + 2 <= c; i += 2) {
            unsigned p = sl[s0 + i + half];
            unsigned v = Xu[((p & 0xFFFFFFu) << 5) | cu];
            alo0 += blo2f(v); ahi0 += bhi2f(v);
        }
        if (i + half < c) {
            unsigned p = sl[s0 + i + half];
            unsigned v = Xu[((p & 0xFFFFFFu) << 5) | cu];
            alo1 += blo2f(v); ahi1 += bhi2f(v);
        }
        float alo = alo0 + alo1;
        float ahi = ahi0 + ahi1;
        float blo = __shfl(alo, lane + 32);
        float bhi = __shfl(ahi, lane + 32);
        if (half == 0) {
            alo += blo; ahi += bhi;
            aggu[(size_t)node * 32 + (int)cu] =
                (unsigned)f2b(alo) | ((unsigned)f2b(ahi) << 16);
        }
    }
}

__global__ __launch_bounds__(256) void mlp_k(
        const ushort_t* __restrict__ aggb,
        const ushort_t* __restrict__ W1, const float* __restrict__ b1,
        const ushort_t* __restrict__ W2, const float* __restrict__ b2,
        float* __restrict__ out, int N) {
    __shared__ ushort_t h_s[4][16 * HPITCH];

    int wave = threadIdx.x >> 6;
    int lane = threadIdx.x & 63;
    int row  = lane & 15;
    int quad = lane >> 4;
    int n0   = blockIdx.x * 64 + wave * 16;

    int anode = n0 + row;
    if (anode > N - 1) anode = N - 1;
    const ushort_t* ap = aggb + (size_t)anode * 64;
    short8 a0 = *(const short8*)(ap + quad * 8);
    short8 a1 = *(const short8*)(ap + 32 + quad * 8);

    float4v zero = {0.f, 0.f, 0.f, 0.f};
    float4v acc[8];
#pragma unroll
    for (int nt = 0; nt < 8; ++nt) acc[nt] = zero;

#pragma unroll
    for (int nt = 0; nt < 8; ++nt) {
        const ushort_t* wp = W1 + (size_t)(nt * 16 + row) * 64 + quad * 8;
        short8 bf0 = *(const short8*)(wp);
        short8 bf1 = *(const short8*)(wp + 32);
        acc[nt] = __builtin_amdgcn_mfma_f32_16x16x32_bf16(a0, bf0, acc[nt], 0, 0, 0);
        acc[nt] = __builtin_amdgcn_mfma_f32_16x16x32_bf16(a1, bf1, acc[nt], 0, 0, 0);
    }

    ushort_t* hw = h_s[wave];
#pragma unroll
    for (int nt = 0; nt < 8; ++nt) {
        float bias = b1[nt * 16 + row];
#pragma unroll
        for (int r = 0; r < 4; ++r) {
            float v = acc[nt][r] + bias;
            v = v > 0.f ? v : 0.f;
            hw[(quad * 4 + r) * HPITCH + nt * 16 + row] = f2b(v);
        }
    }
    __syncthreads();

    short8 a2[4];
#pragma unroll
    for (int kt = 0; kt < 4; ++kt)
        a2[kt] = *(const short8*)(hw + row * HPITCH + kt * 32 + quad * 8);

    float4v acc2[4];
#pragma unroll
    for (int nt = 0; nt < 4; ++nt) acc2[nt] = zero;

#pragma unroll
    for (int nt = 0; nt < 4; ++nt) {
#pragma unroll
        for (int kt = 0; kt < 4; ++kt) {
            short8 bfr = *(const short8*)(W2 + (size_t)(nt * 16 + row) * 128 +
                                          kt * 32 + quad * 8);
            acc2[nt] = __builtin_amdgcn_mfma_f32_16x16x32_bf16(a2[kt], bfr, acc2[nt], 0, 0, 0);
        }
    }

    int node = n0 + quad * 4;
    if (node < N) {
#pragma unroll
        for (int nt = 0; nt < 4; ++nt) {
            int ko = nt * 16 + row;
            float bias = b2[ko];
            float4v pk;
#pragma unroll
            for (int r = 0; r < 4; ++r) pk[r] = acc2[nt][r] + bias;
            *(float4v*)(out + (size_t)ko * N + node) = pk;
        }
    }
}

// ---------------------------------------------------------------------------
extern "C" void kernel_launch(void* const* d_in, const int* in_sizes, int n_in,
                              void* d_out, int out_size, void* d_ws, size_t ws_size,
                              hipStream_t stream) {
    const float* inp = (const float*)d_in[0];   // [64][N] fp32
    const int*   src = (const int*)d_in[1];
    const int*   dst = (const int*)d_in[2];
    const float* W1  = (const float*)d_in[3];   // [128][64] fp32
    const float* b1  = (const float*)d_in[4];   // [128] fp32
    const float* W2  = (const float*)d_in[5];   // [64][128] fp32
    const float* b2  = (const float*)d_in[6];   // [64] fp32
    float* out = (float*)d_out;                 // [64][N] fp32

    int N  = in_sizes[0] / 64;
    int E  = in_sizes[1];
    int NB = (N + BUCKW - 1) >> BSH;            // 1563 for N=100000 (<= NBMAX)
    int TB = (N + 127) / 128;

    size_t xBytes    = (size_t)N * 64 * 2;      // 12.8 MB
    size_t binBytes  = (size_t)NB * CAP * 4;    // 9.6 MB
    size_t fusedNeed = xBytes + binBytes + 2 * 8192 * 2 + NBMAX * 4 + 64;

    if (ws_size >= fusedNeed) {
        // -------- fused path: X + bin live in ws, bam_k writes out --------
        char* w = (char*)d_ws;
        ushort_t* X    = (ushort_t*)w;
        unsigned* bin  = (unsigned*)(w + xBytes);
        ushort_t* w1b  = (ushort_t*)(w + xBytes + binBytes);
        ushort_t* w2b  = w1b + 8192;
        int*      gcur = (int*)(w2b + 8192);

        hipMemsetAsync(gcur, 0, NB * sizeof(int), stream);

        prep_k<<<BINB + TB, 512, 0, stream>>>(inp, X, N, W1, W2, w1b, w2b,
                                              src, dst, gcur, bin, E, NB);

        bam_k<<<NB, 512, 0, stream>>>((const unsigned*)X, bin, gcur,
                                      w1b, b1, w2b, b2, out, N);
    } else {
        // -------- fallback: 3-kernel path (rounds 1-2 verified) --------
        ushort_t* aggb = (ushort_t*)d_ws;
        ushort_t* w1b  = aggb + (size_t)N * 64;
        ushort_t* w2b  = w1b + 8192;
        int*      gcur = (int*)(w2b + 8192);

        char*     ob  = (char*)d_out;
        ushort_t* X   = (ushort_t*)ob;
        unsigned* bin = (unsigned*)(ob + xBytes);

        hipMemsetAsync(gcur, 0, NB * sizeof(int), stream);

        prep_k<<<BINB + TB, 512, 0, stream>>>(inp, X, N, W1, W2, w1b, w2b,
                                              src, dst, gcur, bin, E, NB);

        bagg_k<<<NB, 256, 0, stream>>>((const unsigned*)X, bin, gcur,
                                       (unsigned*)aggb, N);

        int tb = (N + 63) / 64;
        mlp_k<<<tb, 256, 0, stream>>>(aggb, w1b, b1, w2b, b2, out, N);
    }
}

// Round 11
// 185.918 us; speedup vs baseline: 2.0827x; 2.0827x over previous
//
#include <hip/hip_runtime.h>
#include <hip/hip_bf16.h>
#include <stdint.h>

typedef unsigned short ushort_t;
using short8   = __attribute__((ext_vector_type(8))) short;
using float4v  = __attribute__((ext_vector_type(4))) float;
using uint4v   = __attribute__((ext_vector_type(4))) unsigned;
using uint2v   = __attribute__((ext_vector_type(2))) unsigned;

#define BSH    6          // bucket = 64 consecutive dst nodes
#define BUCKW  64
#define CAP    1536       // per-bucket capacity (avg 1024, +16 sigma)
#define NBMAX  2048
#define BINB   384        // binning blocks (512 thr each)
#define HPITCH 136
#define APITCH 36         // agg_s pitch in dwords
#define NKEY   512        // (node 6b << 3) | slice 3b

__device__ __forceinline__ ushort_t f2b(float f) {
    union { float f; unsigned int i; } v;
    v.f = f;
    unsigned int u = v.i;
    unsigned int r = (u + 0x7fffu + ((u >> 16) & 1u)) >> 16;   // RNE
    return (ushort_t)r;
}
__device__ __forceinline__ float blo2f(unsigned v) {
    union { unsigned i; float f; } u; u.i = v << 16; return u.f;
}
__device__ __forceinline__ float bhi2f(unsigned v) {
    union { unsigned i; float f; } u; u.i = v & 0xFFFF0000u; return u.f;
}

// ---------------------------------------------------------------------------
// prep_k: heterogeneous roles, 512 threads (R5/R6/R8 verified two-sweep;
// R10's global-atomic single-sweep reverted: 1024-deep same-address atomic
// chains + scattered 4B writes cost 5x).
// ---------------------------------------------------------------------------
__global__ __launch_bounds__(512) void prep_k(
        const float* __restrict__ inp, ushort_t* __restrict__ X, int N,
        const float* __restrict__ W1, const float* __restrict__ W2,
        ushort_t* __restrict__ w1b, ushort_t* __restrict__ w2b,
        const int* __restrict__ src, const int* __restrict__ dst,
        int* __restrict__ gcur, unsigned* __restrict__ bin, int E,
        int NB) {
    __shared__ int lcnt[NBMAX];
    __shared__ int gbase[NBMAX];
    __shared__ int lcur[NBMAX];
    int tid = threadIdx.x;

    if ((int)blockIdx.x >= BINB) {
        // ---------------- transpose role (register-direct) ----------------
        int tb = blockIdx.x - BINB;
        if (tb == 0) {
            for (int i = tid; i < 8192; i += 512) {
                w1b[i] = f2b(W1[i]);
                w2b[i] = f2b(W2[i]);
            }
        }
        int db = tid >> 7;                  // 0..3: 16-dim block
        int nl = tid & 127;                 // node within block tile
        int nc = tb * 128 + nl;
        if (nc < N) {
            const float* ip = inp + (size_t)(db * 16) * N + nc;
            float v[16];
#pragma unroll
            for (int r = 0; r < 16; ++r)    // 16 independent loads -> in flight
                v[r] = ip[(size_t)r * N];
            unsigned dw[8];
#pragma unroll
            for (int j = 0; j < 8; ++j)
                dw[j] = (unsigned)f2b(v[2 * j]) | ((unsigned)f2b(v[2 * j + 1]) << 16);
            unsigned* xp = (unsigned*)X + (size_t)nc * 32 + db * 8;
            uint4v a = {dw[0], dw[1], dw[2], dw[3]};
            uint4v b = {dw[4], dw[5], dw[6], dw[7]};
            *(uint4v*)(xp)     = a;
            *(uint4v*)(xp + 4) = b;
        }
    } else {
        // ---------------- binning role (two-sweep LDS counting) -----------
        int bid   = blockIdx.x;
        int chunk = (E + BINB - 1) / BINB;
        int s0 = bid * chunk;
        int s1 = s0 + chunk;
        if (s1 > E) s1 = E;

        for (int b = tid; b < NB; b += 512) lcnt[b] = 0;
        __syncthreads();

        int e = s0 + tid;
        for (; e + 512 * 7 < s1; e += 512 * 8) {
            int d[8];
#pragma unroll
            for (int k = 0; k < 8; ++k) d[k] = dst[e + 512 * k];
#pragma unroll
            for (int k = 0; k < 8; ++k) atomicAdd(&lcnt[d[k] >> BSH], 1);
        }
        for (; e < s1; e += 512)
            atomicAdd(&lcnt[dst[e] >> BSH], 1);
        __syncthreads();

        for (int b = tid; b < NB; b += 512) {
            int c = lcnt[b];
            gbase[b] = c ? atomicAdd(&gcur[b], c) : 0;   // relative base
            lcur[b]  = 0;
        }
        __syncthreads();

        e = s0 + tid;
        for (; e + 512 * 7 < s1; e += 512 * 8) {
            int d[8], s[8];
#pragma unroll
            for (int k = 0; k < 8; ++k) {
                d[k] = dst[e + 512 * k];
                s[k] = src[e + 512 * k];
            }
#pragma unroll
            for (int k = 0; k < 8; ++k) {
                int b   = d[k] >> BSH;
                int pos = gbase[b] + atomicAdd(&lcur[b], 1);
                if (pos < CAP)
                    bin[(size_t)b * CAP + pos] =
                        ((unsigned)(d[k] & (BUCKW - 1)) << 24) | (unsigned)s[k];
            }
        }
        for (; e < s1; e += 512) {
            int dv = dst[e];
            int b  = dv >> BSH;
            int pos = gbase[b] + atomicAdd(&lcur[b], 1);
            if (pos < CAP)
                bin[(size_t)b * CAP + pos] =
                    ((unsigned)(dv & (BUCKW - 1)) << 24) | (unsigned)src[e];
        }
    }
}

// ---------------------------------------------------------------------------
// bam_k: fused sort + gather + MLP, 512 threads.
// NEW this round: SLICE-ORDERED sort. Key = (node<<3)|(src>>14): each node's
// edges stay contiguous but are ordered by 2MB source slice, so as waves walk
// their edge lists the whole block sweeps X slice-by-slice -> instantaneous
// gather working set ~2-6MB (L2-resident) instead of 12.8MB random. Targets
// R8's anomaly: FETCH_SIZE 76.6MB vs ~20MB unique (gather missing L2+L3).
// Gather loop itself = exact R8 dwordx2 body (verified sweet spot).
// LDS union (19456 B): sl@0 | sc2[512]@6144 | ecur2[512]@8192 | agg_s@10240;
// h_s (17408) overlays after the post-gather barrier. MLP: R6 wave-pair split.
// ---------------------------------------------------------------------------
__global__ __launch_bounds__(512, 3) void bam_k(
        const unsigned* __restrict__ Xu, const unsigned* __restrict__ bin,
        const int* __restrict__ gcur,
        const ushort_t* __restrict__ W1, const float* __restrict__ b1,
        const ushort_t* __restrict__ W2, const float* __restrict__ b2,
        float* __restrict__ out, int N) {
    __shared__ __align__(16) char P[19456];
    __shared__ int wtot[8];
    __shared__ int woff[8];
    unsigned* sl    = (unsigned*)P;                 // [0, 6144)
    int*      sc2   = (int*)(P + 6144);             // [6144, 8192)  512 keys
    int*      ecur2 = (int*)(P + 8192);             // [8192, 10240)
    unsigned* agg_s = (unsigned*)(P + 10240);       // [10240, 19456)

    int tid = threadIdx.x;
    int b   = blockIdx.x;
    int wave = tid >> 6;               // 0..7
    int lane = tid & 63;

    int cnt = gcur[b];
    if (cnt > CAP) cnt = CAP;
    const unsigned* bb = bin + (size_t)b * CAP;

    sc2[tid] = 0;                       // 512 threads, 512 keys
    __syncthreads();

    for (int i = tid; i < cnt; i += 512) {
        unsigned p = bb[i];
        int key = (int)((p >> 24) << 3) | (int)((p & 0xFFFFFFu) >> 14);
        atomicAdd(&sc2[key], 1);
    }
    __syncthreads();

    // hierarchical exclusive scan over 512 keys: 8 per-wave shfl scans
    {
        int orig = sc2[tid];
        int v = orig;
#pragma unroll
        for (int off = 1; off < 64; off <<= 1) {
            int t = __shfl_up(v, off, 64);
            if (lane >= off) v += t;
        }
        if (lane == 63) wtot[wave] = v;
        __syncthreads();
        if (tid < 8) {
            int tv = wtot[tid];
#pragma unroll
            for (int off = 1; off < 8; off <<= 1) {
                int t = __shfl_up(tv, off, 64);
                if (lane >= off) tv += t;
            }
            woff[tid] = tv - wtot[tid];     // exclusive wave offset
        }
        __syncthreads();
        sc2[tid]   = v - orig + woff[wave]; // exclusive prefix by key
        ecur2[tid] = 0;
    }
    __syncthreads();

    for (int i = tid; i < cnt; i += 512) {
        unsigned p = bb[i];
        int key = (int)((p >> 24) << 3) | (int)((p & 0xFFFFFFu) >> 14);
        int pos = sc2[key] + atomicAdd(&ecur2[key], 1);
        sl[pos] = p;
    }
    __syncthreads();

    const uint2v* Xu2 = (const uint2v*)Xu;   // row = 16 uint2 (128 B)

    int qtr  = lane >> 4;              // 0..3: which of 4 edges per instr
    unsigned du = (unsigned)(lane & 15);   // uint2 index within row (dims 4du..4du+3)
    int row  = lane & 15;
    int quad = lane >> 4;

    for (int n = wave; n < BUCKW; n += 8) {
        int s0 = sc2[n * 8];
        int c  = ((n < BUCKW - 1) ? sc2[n * 8 + 8] : cnt) - s0;
        float a0f = 0.f, a1f = 0.f, a2f = 0.f, a3f = 0.f;
        int i = 0;
        for (; i + 16 <= c; i += 16) {     // 16 edges = 4 load instrs
            unsigned p0 = sl[s0 + i +  0 + qtr];
            unsigned p1 = sl[s0 + i +  4 + qtr];
            unsigned p2 = sl[s0 + i +  8 + qtr];
            unsigned p3 = sl[s0 + i + 12 + qtr];
            uint2v v0 = Xu2[((p0 & 0xFFFFFFu) << 4) | du];
            uint2v v1 = Xu2[((p1 & 0xFFFFFFu) << 4) | du];
            uint2v v2 = Xu2[((p2 & 0xFFFFFFu) << 4) | du];
            uint2v v3 = Xu2[((p3 & 0xFFFFFFu) << 4) | du];
            a0f += blo2f(v0[0]); a1f += bhi2f(v0[0]);
            a2f += blo2f(v0[1]); a3f += bhi2f(v0[1]);
            a0f += blo2f(v1[0]); a1f += bhi2f(v1[0]);
            a2f += blo2f(v1[1]); a3f += bhi2f(v1[1]);
            a0f += blo2f(v2[0]); a1f += bhi2f(v2[0]);
            a2f += blo2f(v2[1]); a3f += bhi2f(v2[1]);
            a0f += blo2f(v3[0]); a1f += bhi2f(v3[0]);
            a2f += blo2f(v3[1]); a3f += bhi2f(v3[1]);
        }
        for (; i + 4 <= c; i += 4) {
            unsigned p = sl[s0 + i + qtr];
            uint2v v = Xu2[((p & 0xFFFFFFu) << 4) | du];
            a0f += blo2f(v[0]); a1f += bhi2f(v[0]);
            a2f += blo2f(v[1]); a3f += bhi2f(v[1]);
        }
        if (i < c && qtr < c - i) {        // tail 1..3 edges
            unsigned p = sl[s0 + i + qtr];
            uint2v v = Xu2[((p & 0xFFFFFFu) << 4) | du];
            a0f += blo2f(v[0]); a1f += bhi2f(v[0]);
            a2f += blo2f(v[1]); a3f += bhi2f(v[1]);
        }
        // butterfly across the 4 qtr-groups (lanes du, du+16, du+32, du+48)
        a0f += __shfl_xor(a0f, 16); a1f += __shfl_xor(a1f, 16);
        a2f += __shfl_xor(a2f, 16); a3f += __shfl_xor(a3f, 16);
        a0f += __shfl_xor(a0f, 32); a1f += __shfl_xor(a1f, 32);
        a2f += __shfl_xor(a2f, 32); a3f += __shfl_xor(a3f, 32);
        if (qtr == 0) {
            agg_s[n * APITCH + 2 * (int)du]     =
                (unsigned)f2b(a0f) | ((unsigned)f2b(a1f) << 16);
            agg_s[n * APITCH + 2 * (int)du + 1] =
                (unsigned)f2b(a2f) | ((unsigned)f2b(a3f) << 16);
        }
    }
    __syncthreads();    // gather complete (sl dead; agg_s valid)

    // ---------------- fused MLP, wave-pair split (R6/R8 verified) ----------------
    int grp    = wave & 3;             // node group: rows grp*16 .. +15
    int g_half = wave >> 2;            // 0: dims/cols 0-63|0-31, 1: the rest

    const unsigned* arow = agg_s + (grp * 16 + row) * APITCH;
    short8 a0 = *(const short8*)(arow + quad * 4);
    short8 a1 = *(const short8*)(arow + 16 + quad * 4);

    __syncthreads();    // all A-fragments in registers; agg_s region now free

    ushort_t* hw = (ushort_t*)P + (size_t)grp * (16 * HPITCH);
    float4v zero = {0.f, 0.f, 0.f, 0.f};

    // layer 1: this wave computes dim-half g_half (64 of 128 hidden dims)
    {
        float4v acc[4];
#pragma unroll
        for (int nt = 0; nt < 4; ++nt) acc[nt] = zero;
#pragma unroll
        for (int nt = 0; nt < 4; ++nt) {
            const ushort_t* wp = W1 + (size_t)(g_half * 64 + nt * 16 + row) * 64 + quad * 8;
            short8 bf0 = *(const short8*)(wp);
            short8 bf1 = *(const short8*)(wp + 32);
            acc[nt] = __builtin_amdgcn_mfma_f32_16x16x32_bf16(a0, bf0, acc[nt], 0, 0, 0);
            acc[nt] = __builtin_amdgcn_mfma_f32_16x16x32_bf16(a1, bf1, acc[nt], 0, 0, 0);
        }
#pragma unroll
        for (int nt = 0; nt < 4; ++nt) {
            float bias = b1[g_half * 64 + nt * 16 + row];
#pragma unroll
            for (int r = 0; r < 4; ++r) {
                float v = acc[nt][r] + bias;
                v = v > 0.f ? v : 0.f;
                hw[(quad * 4 + r) * HPITCH + g_half * 64 + nt * 16 + row] = f2b(v);
            }
        }
    }
    __syncthreads();

    short8 a2[4];
#pragma unroll
    for (int kt = 0; kt < 4; ++kt)
        a2[kt] = *(const short8*)(hw + row * HPITCH + kt * 32 + quad * 8);

    // layer 2: this wave computes out-col tiles {g_half*2, g_half*2+1}
    float4v acc2[2];
#pragma unroll
    for (int nt = 0; nt < 2; ++nt) acc2[nt] = zero;

#pragma unroll
    for (int nt = 0; nt < 2; ++nt) {
        int ntg = g_half * 2 + nt;
#pragma unroll
        for (int kt = 0; kt < 4; ++kt) {
            short8 bfr = *(const short8*)(W2 + (size_t)(ntg * 16 + row) * 128 +
                                          kt * 32 + quad * 8);
            acc2[nt] = __builtin_amdgcn_mfma_f32_16x16x32_bf16(a2[kt], bfr, acc2[nt], 0, 0, 0);
        }
    }

    int n0   = (b << BSH) + grp * 16;
    int node = n0 + quad * 4;
#pragma unroll
    for (int nt = 0; nt < 2; ++nt) {
        int ko = (g_half * 2 + nt) * 16 + row;
        float bias = b2[ko];
        float4v pk;
#pragma unroll
        for (int r = 0; r < 4; ++r) pk[r] = acc2[nt][r] + bias;
        if (node + 3 < N) {
            *(float4v*)(out + (size_t)ko * N + node) = pk;
        } else {
#pragma unroll
            for (int r = 0; r < 4; ++r)
                if (node + r < N) out[(size_t)ko * N + node + r] = pk[r];
        }
    }
}

// ---------------------------------------------------------------------------
// Fallback pair (small-ws path): R1/R2 verified bagg_k + mlp_k.
// ---------------------------------------------------------------------------
__global__ __launch_bounds__(256) void bagg_k(
        const unsigned* __restrict__ Xu, const unsigned* __restrict__ bin,
        const int* __restrict__ gcur, unsigned* __restrict__ aggu, int N) {
    __shared__ unsigned sl[CAP];
    __shared__ int ecnt[BUCKW];
    __shared__ int sc[BUCKW];
    __shared__ int ecur[BUCKW];
    int tid = threadIdx.x;
    int b   = blockIdx.x;
    int lo  = b << BSH;

    int cnt = gcur[b];
    if (cnt > CAP) cnt = CAP;
    const unsigned* bb = bin + (size_t)b * CAP;

    if (tid < BUCKW) ecnt[tid] = 0;
    __syncthreads();
    for (int i = tid; i < cnt; i += 256)
        atomicAdd(&ecnt[bb[i] >> 24], 1);
    __syncthreads();
    if (tid < BUCKW) sc[tid] = ecnt[tid];
    __syncthreads();
#pragma unroll
    for (int off = 1; off < BUCKW; off <<= 1) {
        int v = 0;
        if (tid < BUCKW && tid >= off) v = sc[tid - off];
        __syncthreads();
        if (tid < BUCKW) sc[tid] += v;
        __syncthreads();
    }
    if (tid < BUCKW) { sc[tid] -= ecnt[tid]; ecur[tid] = 0; }
    __syncthreads();
    for (int i = tid; i < cnt; i += 256) {
        unsigned p = bb[i];
        int nl  = (int)(p >> 24);
        int pos = sc[nl] + atomicAdd(&ecur[nl], 1);
        sl[pos] = p;
    }
    __syncthreads();

    int wave = tid >> 6;
    int lane = tid & 63;
    int half = lane >> 5;
    unsigned cu = (unsigned)(lane & 31);

    for (int n = wave; n < BUCKW; n += 4) {
        int node = lo + n;
        if (node >= N) break;
        int s0 = sc[n];
        int c  = ecnt[n];
        float alo0 = 0.f, ahi0 = 0.f, alo1 = 0.f, ahi1 = 0.f;
        int i = 0;
        for (; i + 16 <= c; i += 16) {
            unsigned p0 = sl[s0 + i +  0 + half], p1 = sl[s0 + i +  2 + half];
            unsigned p2 = sl[s0 + i +  4 + half], p3 = sl[s0 + i +  6 + half];
            unsigned p4 = sl[s0 + i +  8 + half], p5 = sl[s0 + i + 10 + half];
            unsigned p6 = sl[s0 + i + 12 + half], p7 = sl[s0 + i + 14 + half];
            unsigned v0 = Xu[((p0 & 0xFFFFFFu) << 5) | cu];
            unsigned v1 = Xu[((p1 & 0xFFFFFFu) << 5) | cu];
            unsigned v2 = Xu[((p2 & 0xFFFFFFu) << 5) | cu];
            unsigned v3 = Xu[((p3 & 0xFFFFFFu) << 5) | cu];
            unsigned v4 = Xu[((p4 & 0xFFFFFFu) << 5) | cu];
            unsigned v5 = Xu[((p5 & 0xFFFFFFu) << 5) | cu];
            unsigned v6 = Xu[((p6 & 0xFFFFFFu) << 5) | cu];
            unsigned v7 = Xu[((p7 & 0xFFFFFFu) << 5) | cu];
            alo0 += blo2f(v0); ahi0 += bhi2f(v0);
            alo1 += blo2f(v1); ahi1 += bhi2f(v1);
            alo0 += blo2f(v2); ahi0 += bhi2f(v2);
            alo1 += blo2f(v3); ahi1 += bhi2f(v3);
            alo0 += blo2f(v4); ahi0 += bhi2f(v4);
            alo1 += blo2f(v5); ahi1 += bhi2f(v5);
            alo0 += blo2f(v6); ahi0 += bhi2f(v6);
            alo1 += blo2f(v7); ahi1 += bhi2f(v7);
        }
        for (; i + 2 <= c; i += 2) {
            unsigned p = sl[s0 + i + half];
            unsigned v = Xu[((p & 0xFFFFFFu) << 5) | cu];
            alo0 += blo2f(v); ahi0 += bhi2f(v);
        }
        if (i + half < c) {
            unsigned p = sl[s0 + i + half];
            unsigned v = Xu[((p & 0xFFFFFFu) << 5) | cu];
            alo1 += blo2f(v); ahi1 += bhi2f(v);
        }
        float alo = alo0 + alo1;
        float ahi = ahi0 + ahi1;
        float blo = __shfl(alo, lane + 32);
        float bhi = __shfl(ahi, lane + 32);
        if (half == 0) {
            alo += blo; ahi += bhi;
            aggu[(size_t)node * 32 + (int)cu] =
                (unsigned)f2b(alo) | ((unsigned)f2b(ahi) << 16);
        }
    }
}

__global__ __launch_bounds__(256) void mlp_k(
        const ushort_t* __restrict__ aggb,
        const ushort_t* __restrict__ W1, const float* __restrict__ b1,
        const ushort_t* __restrict__ W2, const float* __restrict__ b2,
        float* __restrict__ out, int N) {
    __shared__ ushort_t h_s[4][16 * HPITCH];

    int wave = threadIdx.x >> 6;
    int lane = threadIdx.x & 63;
    int row  = lane & 15;
    int quad = lane >> 4;
    int n0   = blockIdx.x * 64 + wave * 16;

    int anode = n0 + row;
    if (anode > N - 1) anode = N - 1;
    const ushort_t* ap = aggb + (size_t)anode * 64;
    short8 a0 = *(const short8*)(ap + quad * 8);
    short8 a1 = *(const short8*)(ap + 32 + quad * 8);

    float4v zero = {0.f, 0.f, 0.f, 0.f};
    float4v acc[8];
#pragma unroll
    for (int nt = 0; nt < 8; ++nt) acc[nt] = zero;

#pragma unroll
    for (int nt = 0; nt < 8; ++nt) {
        const ushort_t* wp = W1 + (size_t)(nt * 16 + row) * 64 + quad * 8;
        short8 bf0 = *(const short8*)(wp);
        short8 bf1 = *(const short8*)(wp + 32);
        acc[nt] = __builtin_amdgcn_mfma_f32_16x16x32_bf16(a0, bf0, acc[nt], 0, 0, 0);
        acc[nt] = __builtin_amdgcn_mfma_f32_16x16x32_bf16(a1, bf1, acc[nt], 0, 0, 0);
    }

    ushort_t* hw = h_s[wave];
#pragma unroll
    for (int nt = 0; nt < 8; ++nt) {
        float bias = b1[nt * 16 + row];
#pragma unroll
        for (int r = 0; r < 4; ++r) {
            float v = acc[nt][r] + bias;
            v = v > 0.f ? v : 0.f;
            hw[(quad * 4 + r) * HPITCH + nt * 16 + row] = f2b(v);
        }
    }
    __syncthreads();

    short8 a2[4];
#pragma unroll
    for (int kt = 0; kt < 4; ++kt)
        a2[kt] = *(const short8*)(hw + row * HPITCH + kt * 32 + quad * 8);

    float4v acc2[4];
#pragma unroll
    for (int nt = 0; nt < 4; ++nt) acc2[nt] = zero;

#pragma unroll
    for (int nt = 0; nt < 4; ++nt) {
#pragma unroll
        for (int kt = 0; kt < 4; ++kt) {
            short8 bfr = *(const short8*)(W2 + (size_t)(nt * 16 + row) * 128 +
                                          kt * 32 + quad * 8);
            acc2[nt] = __builtin_amdgcn_mfma_f32_16x16x32_bf16(a2[kt], bfr, acc2[nt], 0, 0, 0);
        }
    }

    int node = n0 + quad * 4;
    if (node < N) {
#pragma unroll
        for (int nt = 0; nt < 4; ++nt) {
            int ko = nt * 16 + row;
            float bias = b2[ko];
            float4v pk;
#pragma unroll
            for (int r = 0; r < 4; ++r) pk[r] = acc2[nt][r] + bias;
            *(float4v*)(out + (size_t)ko * N + node) = pk;
        }
    }
}

// ---------------------------------------------------------------------------
extern "C" void kernel_launch(void* const* d_in, const int* in_sizes, int n_in,
                              void* d_out, int out_size, void* d_ws, size_t ws_size,
                              hipStream_t stream) {
    const float* inp = (const float*)d_in[0];   // [64][N] fp32
    const int*   src = (const int*)d_in[1];
    const int*   dst = (const int*)d_in[2];
    const float* W1  = (const float*)d_in[3];   // [128][64] fp32
    const float* b1  = (const float*)d_in[4];   // [128] fp32
    const float* W2  = (const float*)d_in[5];   // [64][128] fp32
    const float* b2  = (const float*)d_in[6];   // [64] fp32
    float* out = (float*)d_out;                 // [64][N] fp32

    int N  = in_sizes[0] / 64;
    int E  = in_sizes[1];
    int NB = (N + BUCKW - 1) >> BSH;            // 1563 for N=100000 (<= NBMAX)
    int TB = (N + 127) / 128;

    size_t xBytes    = (size_t)N * 64 * 2;      // 12.8 MB
    size_t binBytes  = (size_t)NB * CAP * 4;    // 9.6 MB
    size_t fusedNeed = xBytes + binBytes + 2 * 8192 * 2 + NBMAX * 4 + 64;

    if (ws_size >= fusedNeed) {
        // -------- fused path: X + bin live in ws, bam_k writes out --------
        char* w = (char*)d_ws;
        ushort_t* X    = (ushort_t*)w;
        unsigned* bin  = (unsigned*)(w + xBytes);
        ushort_t* w1b  = (ushort_t*)(w + xBytes + binBytes);
        ushort_t* w2b  = w1b + 8192;
        int*      gcur = (int*)(w2b + 8192);

        hipMemsetAsync(gcur, 0, NB * sizeof(int), stream);

        prep_k<<<BINB + TB, 512, 0, stream>>>(inp, X, N, W1, W2, w1b, w2b,
                                              src, dst, gcur, bin, E, NB);

        bam_k<<<NB, 512, 0, stream>>>((const unsigned*)X, bin, gcur,
                                      w1b, b1, w2b, b2, out, N);
    } else {
        // -------- fallback: 3-kernel path (rounds 1-2 verified) --------
        ushort_t* aggb = (ushort_t*)d_ws;
        ushort_t* w1b  = aggb + (size_t)N * 64;
        ushort_t* w2b  = w1b + 8192;
        int*      gcur = (int*)(w2b + 8192);

        char*     ob  = (char*)d_out;
        ushort_t* X   = (ushort_t*)ob;
        unsigned* bin = (unsigned*)(ob + xBytes);

        hipMemsetAsync(gcur, 0, NB * sizeof(int), stream);

        prep_k<<<BINB + TB, 512, 0, stream>>>(inp, X, N, W1, W2, w1b, w2b,
                                              src, dst, gcur, bin, E, NB);

        bagg_k<<<NB, 256, 0, stream>>>((const unsigned*)X, bin, gcur,
                                       (unsigned*)aggb, N);

        int tb = (N + 63) / 64;
        mlp_k<<<tb, 256, 0, stream>>>(aggb, w1b, b1, w2b, b2, out, N);
    }
}

// Round 12
// 182.160 us; speedup vs baseline: 2.1256x; 1.0206x over previous
//
#include <hip/hip_runtime.h>
#include <hip/hip_bf16.h>
#include <stdint.h>

typedef unsigned short ushort_t;
using short8   = __attribute__((ext_vector_type(8))) short;
using float4v  = __attribute__((ext_vector_type(4))) float;
using uint4v   = __attribute__((ext_vector_type(4))) unsigned;
using uint2v   = __attribute__((ext_vector_type(2))) unsigned;

#define BSH    6          // bucket = 64 consecutive dst nodes
#define BUCKW  64
#define CAP    1536       // per-bucket capacity (avg 1024, +16 sigma)
#define NBMAX  2048
#define BINB   512        // binning blocks (512 thr each; was 384)
#define HPITCH 136
#define APITCH 36         // agg_s pitch in dwords

__device__ __forceinline__ ushort_t f2b(float f) {
    union { float f; unsigned int i; } v;
    v.f = f;
    unsigned int u = v.i;
    unsigned int r = (u + 0x7fffu + ((u >> 16) & 1u)) >> 16;   // RNE
    return (ushort_t)r;
}
__device__ __forceinline__ float blo2f(unsigned v) {
    union { unsigned i; float f; } u; u.i = v << 16; return u.f;
}
__device__ __forceinline__ float bhi2f(unsigned v) {
    union { unsigned i; float f; } u; u.i = v & 0xFFFF0000u; return u.f;
}

// ---------------------------------------------------------------------------
// prep_k: heterogeneous roles, 512 threads (R5/R6/R8 verified two-sweep
// binning + register-direct transpose). Only change: BINB 384->512 (finer
// binning grain; same body).
// ---------------------------------------------------------------------------
__global__ __launch_bounds__(512) void prep_k(
        const float* __restrict__ inp, ushort_t* __restrict__ X, int N,
        const float* __restrict__ W1, const float* __restrict__ W2,
        ushort_t* __restrict__ w1b, ushort_t* __restrict__ w2b,
        const int* __restrict__ src, const int* __restrict__ dst,
        int* __restrict__ gcur, unsigned* __restrict__ bin, int E,
        int NB) {
    __shared__ int lcnt[NBMAX];
    __shared__ int gbase[NBMAX];
    __shared__ int lcur[NBMAX];
    int tid = threadIdx.x;

    if ((int)blockIdx.x >= BINB) {
        // ---------------- transpose role (register-direct) ----------------
        int tb = blockIdx.x - BINB;
        if (tb == 0) {
            for (int i = tid; i < 8192; i += 512) {
                w1b[i] = f2b(W1[i]);
                w2b[i] = f2b(W2[i]);
            }
        }
        int db = tid >> 7;                  // 0..3: 16-dim block
        int nl = tid & 127;                 // node within block tile
        int nc = tb * 128 + nl;
        if (nc < N) {
            const float* ip = inp + (size_t)(db * 16) * N + nc;
            float v[16];
#pragma unroll
            for (int r = 0; r < 16; ++r)    // 16 independent loads -> in flight
                v[r] = ip[(size_t)r * N];
            unsigned dw[8];
#pragma unroll
            for (int j = 0; j < 8; ++j)
                dw[j] = (unsigned)f2b(v[2 * j]) | ((unsigned)f2b(v[2 * j + 1]) << 16);
            unsigned* xp = (unsigned*)X + (size_t)nc * 32 + db * 8;
            uint4v a = {dw[0], dw[1], dw[2], dw[3]};
            uint4v b = {dw[4], dw[5], dw[6], dw[7]};
            *(uint4v*)(xp)     = a;
            *(uint4v*)(xp + 4) = b;
        }
    } else {
        // ---------------- binning role (two-sweep LDS counting) -----------
        int bid   = blockIdx.x;
        int chunk = (E + BINB - 1) / BINB;
        int s0 = bid * chunk;
        int s1 = s0 + chunk;
        if (s1 > E) s1 = E;

        for (int b = tid; b < NB; b += 512) lcnt[b] = 0;
        __syncthreads();

        int e = s0 + tid;
        for (; e + 512 * 7 < s1; e += 512 * 8) {
            int d[8];
#pragma unroll
            for (int k = 0; k < 8; ++k) d[k] = dst[e + 512 * k];
#pragma unroll
            for (int k = 0; k < 8; ++k) atomicAdd(&lcnt[d[k] >> BSH], 1);
        }
        for (; e < s1; e += 512)
            atomicAdd(&lcnt[dst[e] >> BSH], 1);
        __syncthreads();

        for (int b = tid; b < NB; b += 512) {
            int c = lcnt[b];
            gbase[b] = c ? atomicAdd(&gcur[b], c) : 0;   // relative base
            lcur[b]  = 0;
        }
        __syncthreads();

        e = s0 + tid;
        for (; e + 512 * 7 < s1; e += 512 * 8) {
            int d[8], s[8];
#pragma unroll
            for (int k = 0; k < 8; ++k) {
                d[k] = dst[e + 512 * k];
                s[k] = src[e + 512 * k];
            }
#pragma unroll
            for (int k = 0; k < 8; ++k) {
                int b   = d[k] >> BSH;
                int pos = gbase[b] + atomicAdd(&lcur[b], 1);
                if (pos < CAP)
                    bin[(size_t)b * CAP + pos] =
                        ((unsigned)(d[k] & (BUCKW - 1)) << 24) | (unsigned)s[k];
            }
        }
        for (; e < s1; e += 512) {
            int dv = dst[e];
            int b  = dv >> BSH;
            int pos = gbase[b] + atomicAdd(&lcur[b], 1);
            if (pos < CAP)
                bin[(size_t)b * CAP + pos] =
                    ((unsigned)(dv & (BUCKW - 1)) << 24) | (unsigned)src[e];
        }
    }
}

// ---------------------------------------------------------------------------
// bam_k: fused sort + gather + MLP, 512 threads — R8-verified structure
// (64-key node sort; R11's slice-sort was a measured null and is reverted).
// NEW this round: 32-edge inner stage = 8 dwordx2 loads in flight per wave
// (R8 kept 4). Tests the last un-probed gather lever: per-wave MLP at fixed
// instruction width. LDS union (17408 B): sl@0 | ecnt/sc/ecur@6144 |
// agg_s@6912; h_s overlays after the post-gather barrier. MLP: R6 wave-pair
// split (verified).
// ---------------------------------------------------------------------------
__global__ __launch_bounds__(512, 3) void bam_k(
        const unsigned* __restrict__ Xu, const unsigned* __restrict__ bin,
        const int* __restrict__ gcur,
        const ushort_t* __restrict__ W1, const float* __restrict__ b1,
        const ushort_t* __restrict__ W2, const float* __restrict__ b2,
        float* __restrict__ out, int N) {
    __shared__ __align__(16) char P[17408];
    unsigned* sl    = (unsigned*)P;                 // [0, 6144)
    int*      ecnt  = (int*)(P + 6144);             // [6144, 6400)
    int*      sc    = (int*)(P + 6400);             // [6400, 6656)
    int*      ecur  = (int*)(P + 6656);             // [6656, 6912)
    unsigned* agg_s = (unsigned*)(P + 6912);        // [6912, 16128)

    int tid = threadIdx.x;
    int b   = blockIdx.x;

    int cnt = gcur[b];
    if (cnt > CAP) cnt = CAP;
    const unsigned* bb = bin + (size_t)b * CAP;

    if (tid < BUCKW) ecnt[tid] = 0;
    __syncthreads();

    for (int i = tid; i < cnt; i += 512)
        atomicAdd(&ecnt[bb[i] >> 24], 1);
    __syncthreads();

    if (tid < BUCKW) {                      // single-wave inclusive scan
        int v = ecnt[tid];
#pragma unroll
        for (int off = 1; off < BUCKW; off <<= 1) {
            int t = __shfl_up(v, off, 64);
            if (tid >= off) v += t;
        }
        sc[tid]   = v - ecnt[tid];          // exclusive
        ecur[tid] = 0;
    }
    __syncthreads();

    for (int i = tid; i < cnt; i += 512) {
        unsigned p = bb[i];
        int nl  = (int)(p >> 24);
        int pos = sc[nl] + atomicAdd(&ecur[nl], 1);
        sl[pos] = p;
    }
    __syncthreads();

    const uint2v* Xu2 = (const uint2v*)Xu;   // row = 16 uint2 (128 B)

    int wave = tid >> 6;               // 0..7
    int lane = tid & 63;
    int qtr  = lane >> 4;              // 0..3: which of 4 edges per instr
    unsigned du = (unsigned)(lane & 15);   // uint2 index within row (dims 4du..4du+3)
    int row  = lane & 15;
    int quad = lane >> 4;

    for (int n = wave; n < BUCKW; n += 8) {
        int s0 = sc[n];
        int c  = ecnt[n];              // 0 for out-of-range nodes -> zeros
        float a0f = 0.f, a1f = 0.f, a2f = 0.f, a3f = 0.f;
        int i = 0;
        for (; i + 32 <= c; i += 32) {     // 32 edges = 8 load instrs in flight
            unsigned p0 = sl[s0 + i +  0 + qtr];
            unsigned p1 = sl[s0 + i +  4 + qtr];
            unsigned p2 = sl[s0 + i +  8 + qtr];
            unsigned p3 = sl[s0 + i + 12 + qtr];
            unsigned p4 = sl[s0 + i + 16 + qtr];
            unsigned p5 = sl[s0 + i + 20 + qtr];
            unsigned p6 = sl[s0 + i + 24 + qtr];
            unsigned p7 = sl[s0 + i + 28 + qtr];
            uint2v v0 = Xu2[((p0 & 0xFFFFFFu) << 4) | du];
            uint2v v1 = Xu2[((p1 & 0xFFFFFFu) << 4) | du];
            uint2v v2 = Xu2[((p2 & 0xFFFFFFu) << 4) | du];
            uint2v v3 = Xu2[((p3 & 0xFFFFFFu) << 4) | du];
            uint2v v4 = Xu2[((p4 & 0xFFFFFFu) << 4) | du];
            uint2v v5 = Xu2[((p5 & 0xFFFFFFu) << 4) | du];
            uint2v v6 = Xu2[((p6 & 0xFFFFFFu) << 4) | du];
            uint2v v7 = Xu2[((p7 & 0xFFFFFFu) << 4) | du];
            a0f += blo2f(v0[0]); a1f += bhi2f(v0[0]);
            a2f += blo2f(v0[1]); a3f += bhi2f(v0[1]);
            a0f += blo2f(v1[0]); a1f += bhi2f(v1[0]);
            a2f += blo2f(v1[1]); a3f += bhi2f(v1[1]);
            a0f += blo2f(v2[0]); a1f += bhi2f(v2[0]);
            a2f += blo2f(v2[1]); a3f += bhi2f(v2[1]);
            a0f += blo2f(v3[0]); a1f += bhi2f(v3[0]);
            a2f += blo2f(v3[1]); a3f += bhi2f(v3[1]);
            a0f += blo2f(v4[0]); a1f += bhi2f(v4[0]);
            a2f += blo2f(v4[1]); a3f += bhi2f(v4[1]);
            a0f += blo2f(v5[0]); a1f += bhi2f(v5[0]);
            a2f += blo2f(v5[1]); a3f += bhi2f(v5[1]);
            a0f += blo2f(v6[0]); a1f += bhi2f(v6[0]);
            a2f += blo2f(v6[1]); a3f += bhi2f(v6[1]);
            a0f += blo2f(v7[0]); a1f += bhi2f(v7[0]);
            a2f += blo2f(v7[1]); a3f += bhi2f(v7[1]);
        }
        for (; i + 16 <= c; i += 16) {     // 16 edges = 4 load instrs
            unsigned p0 = sl[s0 + i +  0 + qtr];
            unsigned p1 = sl[s0 + i +  4 + qtr];
            unsigned p2 = sl[s0 + i +  8 + qtr];
            unsigned p3 = sl[s0 + i + 12 + qtr];
            uint2v v0 = Xu2[((p0 & 0xFFFFFFu) << 4) | du];
            uint2v v1 = Xu2[((p1 & 0xFFFFFFu) << 4) | du];
            uint2v v2 = Xu2[((p2 & 0xFFFFFFu) << 4) | du];
            uint2v v3 = Xu2[((p3 & 0xFFFFFFu) << 4) | du];
            a0f += blo2f(v0[0]); a1f += bhi2f(v0[0]);
            a2f += blo2f(v0[1]); a3f += bhi2f(v0[1]);
            a0f += blo2f(v1[0]); a1f += bhi2f(v1[0]);
            a2f += blo2f(v1[1]); a3f += bhi2f(v1[1]);
            a0f += blo2f(v2[0]); a1f += bhi2f(v2[0]);
            a2f += blo2f(v2[1]); a3f += bhi2f(v2[1]);
            a0f += blo2f(v3[0]); a1f += bhi2f(v3[0]);
            a2f += blo2f(v3[1]); a3f += bhi2f(v3[1]);
        }
        for (; i + 4 <= c; i += 4) {
            unsigned p = sl[s0 + i + qtr];
            uint2v v = Xu2[((p & 0xFFFFFFu) << 4) | du];
            a0f += blo2f(v[0]); a1f += bhi2f(v[0]);
            a2f += blo2f(v[1]); a3f += bhi2f(v[1]);
        }
        if (i < c && qtr < c - i) {        // tail 1..3 edges
            unsigned p = sl[s0 + i + qtr];
            uint2v v = Xu2[((p & 0xFFFFFFu) << 4) | du];
            a0f += blo2f(v[0]); a1f += bhi2f(v[0]);
            a2f += blo2f(v[1]); a3f += bhi2f(v[1]);
        }
        // butterfly across the 4 qtr-groups (lanes du, du+16, du+32, du+48)
        a0f += __shfl_xor(a0f, 16); a1f += __shfl_xor(a1f, 16);
        a2f += __shfl_xor(a2f, 16); a3f += __shfl_xor(a3f, 16);
        a0f += __shfl_xor(a0f, 32); a1f += __shfl_xor(a1f, 32);
        a2f += __shfl_xor(a2f, 32); a3f += __shfl_xor(a3f, 32);
        if (qtr == 0) {
            agg_s[n * APITCH + 2 * (int)du]     =
                (unsigned)f2b(a0f) | ((unsigned)f2b(a1f) << 16);
            agg_s[n * APITCH + 2 * (int)du + 1] =
                (unsigned)f2b(a2f) | ((unsigned)f2b(a3f) << 16);
        }
    }
    __syncthreads();    // gather complete (sl dead; agg_s valid)

    // ---------------- fused MLP, wave-pair split (R6/R8 verified) ----------------
    int grp    = wave & 3;             // node group: rows grp*16 .. +15
    int g_half = wave >> 2;            // 0: dims/cols 0-63|0-31, 1: the rest

    const unsigned* arow = agg_s + (grp * 16 + row) * APITCH;
    short8 a0 = *(const short8*)(arow + quad * 4);
    short8 a1 = *(const short8*)(arow + 16 + quad * 4);

    __syncthreads();    // all A-fragments in registers; agg_s region now free

    ushort_t* hw = (ushort_t*)P + (size_t)grp * (16 * HPITCH);
    float4v zero = {0.f, 0.f, 0.f, 0.f};

    // layer 1: this wave computes dim-half g_half (64 of 128 hidden dims)
    {
        float4v acc[4];
#pragma unroll
        for (int nt = 0; nt < 4; ++nt) acc[nt] = zero;
#pragma unroll
        for (int nt = 0; nt < 4; ++nt) {
            const ushort_t* wp = W1 + (size_t)(g_half * 64 + nt * 16 + row) * 64 + quad * 8;
            short8 bf0 = *(const short8*)(wp);
            short8 bf1 = *(const short8*)(wp + 32);
            acc[nt] = __builtin_amdgcn_mfma_f32_16x16x32_bf16(a0, bf0, acc[nt], 0, 0, 0);
            acc[nt] = __builtin_amdgcn_mfma_f32_16x16x32_bf16(a1, bf1, acc[nt], 0, 0, 0);
        }
#pragma unroll
        for (int nt = 0; nt < 4; ++nt) {
            float bias = b1[g_half * 64 + nt * 16 + row];
#pragma unroll
            for (int r = 0; r < 4; ++r) {
                float v = acc[nt][r] + bias;
                v = v > 0.f ? v : 0.f;
                hw[(quad * 4 + r) * HPITCH + g_half * 64 + nt * 16 + row] = f2b(v);
            }
        }
    }
    __syncthreads();

    short8 a2[4];
#pragma unroll
    for (int kt = 0; kt < 4; ++kt)
        a2[kt] = *(const short8*)(hw + row * HPITCH + kt * 32 + quad * 8);

    // layer 2: this wave computes out-col tiles {g_half*2, g_half*2+1}
    float4v acc2[2];
#pragma unroll
    for (int nt = 0; nt < 2; ++nt) acc2[nt] = zero;

#pragma unroll
    for (int nt = 0; nt < 2; ++nt) {
        int ntg = g_half * 2 + nt;
#pragma unroll
        for (int kt = 0; kt < 4; ++kt) {
            short8 bfr = *(const short8*)(W2 + (size_t)(ntg * 16 + row) * 128 +
                                          kt * 32 + quad * 8);
            acc2[nt] = __builtin_amdgcn_mfma_f32_16x16x32_bf16(a2[kt], bfr, acc2[nt], 0, 0, 0);
        }
    }

    int n0   = (b << BSH) + grp * 16;
    int node = n0 + quad * 4;
#pragma unroll
    for (int nt = 0; nt < 2; ++nt) {
        int ko = (g_half * 2 + nt) * 16 + row;
        float bias = b2[ko];
        float4v pk;
#pragma unroll
        for (int r = 0; r < 4; ++r) pk[r] = acc2[nt][r] + bias;
        if (node + 3 < N) {
            *(float4v*)(out + (size_t)ko * N + node) = pk;
        } else {
#pragma unroll
            for (int r = 0; r < 4; ++r)
                if (node + r < N) out[(size_t)ko * N + node + r] = pk[r];
        }
    }
}

// ---------------------------------------------------------------------------
// Fallback pair (small-ws path): R1/R2 verified bagg_k + mlp_k.
// ---------------------------------------------------------------------------
__global__ __launch_bounds__(256) void bagg_k(
        const unsigned* __restrict__ Xu, const unsigned* __restrict__ bin,
        const int* __restrict__ gcur, unsigned* __restrict__ aggu, int N) {
    __shared__ unsigned sl[CAP];
    __shared__ int ecnt[BUCKW];
    __shared__ int sc[BUCKW];
    __shared__ int ecur[BUCKW];
    int tid = threadIdx.x;
    int b   = blockIdx.x;
    int lo  = b << BSH;

    int cnt = gcur[b];
    if (cnt > CAP) cnt = CAP;
    const unsigned* bb = bin + (size_t)b * CAP;

    if (tid < BUCKW) ecnt[tid] = 0;
    __syncthreads();
    for (int i = tid; i < cnt; i += 256)
        atomicAdd(&ecnt[bb[i] >> 24], 1);
    __syncthreads();
    if (tid < BUCKW) sc[tid] = ecnt[tid];
    __syncthreads();
#pragma unroll
    for (int off = 1; off < BUCKW; off <<= 1) {
        int v = 0;
        if (tid < BUCKW && tid >= off) v = sc[tid - off];
        __syncthreads();
        if (tid < BUCKW) sc[tid] += v;
        __syncthreads();
    }
    if (tid < BUCKW) { sc[tid] -= ecnt[tid]; ecur[tid] = 0; }
    __syncthreads();
    for (int i = tid; i < cnt; i += 256) {
        unsigned p = bb[i];
        int nl  = (int)(p >> 24);
        int pos = sc[nl] + atomicAdd(&ecur[nl], 1);
        sl[pos] = p;
    }
    __syncthreads();

    int wave = tid >> 6;
    int lane = tid & 63;
    int half = lane >> 5;
    unsigned cu = (unsigned)(lane & 31);

    for (int n = wave; n < BUCKW; n += 4) {
        int node = lo + n;
        if (node >= N) break;
        int s0 = sc[n];
        int c  = ecnt[n];
        float alo0 = 0.f, ahi0 = 0.f, alo1 = 0.f, ahi1 = 0.f;
        int i = 0;
        for (; i + 16 <= c; i += 16) {
            unsigned p0 = sl[s0 + i +  0 + half], p1 = sl[s0 + i +  2 + half];
            unsigned p2 = sl[s0 + i +  4 + half], p3 = sl[s0 + i +  6 + half];
            unsigned p4 = sl[s0 + i +  8 + half], p5 = sl[s0 + i + 10 + half];
            unsigned p6 = sl[s0 + i + 12 + half], p7 = sl[s0 + i + 14 + half];
            unsigned v0 = Xu[((p0 & 0xFFFFFFu) << 5) | cu];
            unsigned v1 = Xu[((p1 & 0xFFFFFFu) << 5) | cu];
            unsigned v2 = Xu[((p2 & 0xFFFFFFu) << 5) | cu];
            unsigned v3 = Xu[((p3 & 0xFFFFFFu) << 5) | cu];
            unsigned v4 = Xu[((p4 & 0xFFFFFFu) << 5) | cu];
            unsigned v5 = Xu[((p5 & 0xFFFFFFu) << 5) | cu];
            unsigned v6 = Xu[((p6 & 0xFFFFFFu) << 5) | cu];
            unsigned v7 = Xu[((p7 & 0xFFFFFFu) << 5) | cu];
            alo0 += blo2f(v0); ahi0 += bhi2f(v0);
            alo1 += blo2f(v1); ahi1 += bhi2f(v1);
            alo0 += blo2f(v2); ahi0 += bhi2f(v2);
            alo1 += blo2f(v3); ahi1 += bhi2f(v3);
            alo0 += blo2f(v4); ahi0 += bhi2f(v4);
            alo1 += blo2f(v5); ahi1 += bhi2f(v5);
            alo0 += blo2f(v6); ahi0 += bhi2f(v6);
            alo1 += blo2f(v7); ahi1 += bhi2f(v7);
        }
        for (; i + 2 <= c; i += 2) {
            unsigned p = sl[s0 + i + half];
            unsigned v = Xu[((p & 0xFFFFFFu) << 5) | cu];
            alo0 += blo2f(v); ahi0 += bhi2f(v);
        }
        if (i + half < c) {
            unsigned p = sl[s0 + i + half];
            unsigned v = Xu[((p & 0xFFFFFFu) << 5) | cu];
            alo1 += blo2f(v); ahi1 += bhi2f(v);
        }
        float alo = alo0 + alo1;
        float ahi = ahi0 + ahi1;
        float blo = __shfl(alo, lane + 32);
        float bhi = __shfl(ahi, lane + 32);
        if (half == 0) {
            alo += blo; ahi += bhi;
            aggu[(size_t)node * 32 + (int)cu] =
                (unsigned)f2b(alo) | ((unsigned)f2b(ahi) << 16);
        }
    }
}

__global__ __launch_bounds__(256) void mlp_k(
        const ushort_t* __restrict__ aggb,
        const ushort_t* __restrict__ W1, const float* __restrict__ b1,
        const ushort_t* __restrict__ W2, const float* __restrict__ b2,
        float* __restrict__ out, int N) {
    __shared__ ushort_t h_s[4][16 * HPITCH];

    int wave = threadIdx.x >> 6;
    int lane = threadIdx.x & 63;
    int row  = lane & 15;
    int quad = lane >> 4;
    int n0   = blockIdx.x * 64 + wave * 16;

    int anode = n0 + row;
    if (anode > N - 1) anode = N - 1;
    const ushort_t* ap = aggb + (size_t)anode * 64;
    short8 a0 = *(const short8*)(ap + quad * 8);
    short8 a1 = *(const short8*)(ap + 32 + quad * 8);

    float4v zero = {0.f, 0.f, 0.f, 0.f};
    float4v acc[8];
#pragma unroll
    for (int nt = 0; nt < 8; ++nt) acc[nt] = zero;

#pragma unroll
    for (int nt = 0; nt < 8; ++nt) {
        const ushort_t* wp = W1 + (size_t)(nt * 16 + row) * 64 + quad * 8;
        short8 bf0 = *(const short8*)(wp);
        short8 bf1 = *(const short8*)(wp + 32);
        acc[nt] = __builtin_amdgcn_mfma_f32_16x16x32_bf16(a0, bf0, acc[nt], 0, 0, 0);
        acc[nt] = __builtin_amdgcn_mfma_f32_16x16x32_bf16(a1, bf1, acc[nt], 0, 0, 0);
    }

    ushort_t* hw = h_s[wave];
#pragma unroll
    for (int nt = 0; nt < 8; ++nt) {
        float bias = b1[nt * 16 + row];
#pragma unroll
        for (int r = 0; r < 4; ++r) {
            float v = acc[nt][r] + bias;
            v = v > 0.f ? v : 0.f;
            hw[(quad * 4 + r) * HPITCH + nt * 16 + row] = f2b(v);
        }
    }
    __syncthreads();

    short8 a2[4];
#pragma unroll
    for (int kt = 0; kt < 4; ++kt)
        a2[kt] = *(const short8*)(hw + row * HPITCH + kt * 32 + quad * 8);

    float4v acc2[4];
#pragma unroll
    for (int nt = 0; nt < 4; ++nt) acc2[nt] = zero;

#pragma unroll
    for (int nt = 0; nt < 4; ++nt) {
#pragma unroll
        for (int kt = 0; kt < 4; ++kt) {
            short8 bfr = *(const short8*)(W2 + (size_t)(nt * 16 + row) * 128 +
                                          kt * 32 + quad * 8);
            acc2[nt] = __builtin_amdgcn_mfma_f32_16x16x32_bf16(a2[kt], bfr, acc2[nt], 0, 0, 0);
        }
    }

    int node = n0 + quad * 4;
    if (node < N) {
#pragma unroll
        for (int nt = 0; nt < 4; ++nt) {
            int ko = nt * 16 + row;
            float bias = b2[ko];
            float4v pk;
#pragma unroll
            for (int r = 0; r < 4; ++r) pk[r] = acc2[nt][r] + bias;
            *(float4v*)(out + (size_t)ko * N + node) = pk;
        }
    }
}

// ---------------------------------------------------------------------------
extern "C" void kernel_launch(void* const* d_in, const int* in_sizes, int n_in,
                              void* d_out, int out_size, void* d_ws, size_t ws_size,
                              hipStream_t stream) {
    const float* inp = (const float*)d_in[0];   // [64][N] fp32
    const int*   src = (const int*)d_in[1];
    const int*   dst = (const int*)d_in[2];
    const float* W1  = (const float*)d_in[3];   // [128][64] fp32
    const float* b1  = (const float*)d_in[4];   // [128] fp32
    const float* W2  = (const float*)d_in[5];   // [64][128] fp32
    const float* b2  = (const float*)d_in[6];   // [64] fp32
    float* out = (float*)d_out;                 // [64][N] fp32

    int N  = in_sizes[0] / 64;
    int E  = in_sizes[1];
    int NB = (N + BUCKW - 1) >> BSH;            // 1563 for N=100000 (<= NBMAX)
    int TB = (N + 127) / 128;

    size_t xBytes    = (size_t)N * 64 * 2;      // 12.8 MB
    size_t binBytes  = (size_t)NB * CAP * 4;    // 9.6 MB
    size_t fusedNeed = xBytes + binBytes + 2 * 8192 * 2 + NBMAX * 4 + 64;

    if (ws_size >= fusedNeed) {
        // -------- fused path: X + bin live in ws, bam_k writes out --------
        char* w = (char*)d_ws;
        ushort_t* X    = (ushort_t*)w;
        unsigned* bin  = (unsigned*)(w + xBytes);
        ushort_t* w1b  = (ushort_t*)(w + xBytes + binBytes);
        ushort_t* w2b  = w1b + 8192;
        int*      gcur = (int*)(w2b + 8192);

        hipMemsetAsync(gcur, 0, NB * sizeof(int), stream);

        prep_k<<<BINB + TB, 512, 0, stream>>>(inp, X, N, W1, W2, w1b, w2b,
                                              src, dst, gcur, bin, E, NB);

        bam_k<<<NB, 512, 0, stream>>>((const unsigned*)X, bin, gcur,
                                      w1b, b1, w2b, b2, out, N);
    } else {
        // -------- fallback: 3-kernel path (rounds 1-2 verified) --------
        ushort_t* aggb = (ushort_t*)d_ws;
        ushort_t* w1b  = aggb + (size_t)N * 64;
        ushort_t* w2b  = w1b + 8192;
        int*      gcur = (int*)(w2b + 8192);

        char*     ob  = (char*)d_out;
        ushort_t* X   = (ushort_t*)ob;
        unsigned* bin = (unsigned*)(ob + xBytes);

        hipMemsetAsync(gcur, 0, NB * sizeof(int), stream);

        prep_k<<<BINB + TB, 512, 0, stream>>>(inp, X, N, W1, W2, w1b, w2b,
                                              src, dst, gcur, bin, E, NB);

        bagg_k<<<NB, 256, 0, stream>>>((const unsigned*)X, bin, gcur,
                                       (unsigned*)aggb, N);

        int tb = (N + 63) / 64;
        mlp_k<<<tb, 256, 0, stream>>>(aggb, w1b, b1, w2b, b2, out, N);
    }
}